// Round 8
// baseline (383.940 us; speedup 1.0000x reference)
//
#include <hip/hip_runtime.h>
#include <stdint.h>

#define NUM_CAP 16
#define DIM_CAP 64
#define BATCH   64
#define N_IN    512
#define D_IN    1024
#define N_COL   1024
#define M_ROWS  (BATCH*N_IN)

typedef __attribute__((ext_vector_type(8))) short short8;
typedef __attribute__((ext_vector_type(4))) float f32x4;

__device__ __forceinline__ float bf2f(unsigned int u) {
  return __uint_as_float(u << 16);
}
__device__ __forceinline__ unsigned short f2bf_rne(float f) {
  unsigned int x = __float_as_uint(f);
  x += 0x7fffu + ((x >> 16) & 1u);
  return (unsigned short)(x >> 16);
}
__device__ __forceinline__ unsigned int pack_trunc(unsigned int lo, unsigned int hi) {
  return (lo >> 16) | (hi & 0xffff0000u);
}

// ---------------------------------------------------------------------------
// prep_w: W fp32 [D_IN][N_COL] -> Wt bf16 [N_COL][D_IN] (transpose + RNE).
// ---------------------------------------------------------------------------
__global__ __launch_bounds__(256) void prep_w(
    const float* __restrict__ W, unsigned short* __restrict__ Wt) {
  __shared__ float tile[32][33];
  const int t = threadIdx.x;
  const int bx = blockIdx.x & 31, by = blockIdx.x >> 5;
  const int tx = t & 31, ty0 = t >> 5;
  #pragma unroll
  for (int r = 0; r < 4; r++) {
    const int ty = ty0 + r * 8;
    tile[ty][tx] = W[(size_t)(by * 32 + ty) * N_COL + bx * 32 + tx];
  }
  __syncthreads();
  #pragma unroll
  for (int r = 0; r < 4; r++) {
    const int ty = ty0 + r * 8;
    Wt[(size_t)(bx * 32 + ty) * D_IN + by * 32 + tx] = f2bf_rne(tile[tx][ty]);
  }
}

// ---------------------------------------------------------------------------
// GEMM: uhat[m][n] = sum_k x[m][k] * Wt[n][k].
// A read as fp32 DIRECTLY via async global_load_lds (width 16 = 4 floats)
// into a 16 KB fp32 tile -- removes the conv_x pass entirely; truncate-pack
// to bf16 happens during the fragment read (R2/R4/R5-proven numerics).
// A-LDS swizzle: 16-B chunk c of row r stored at position c^(r&7) ->
// fragment b128 reads spread over all banks, <=2-way.  B path unchanged from
// R3/R7 (bf16 global_load_lds, c^((r>>1)&3) swizzle, conflicts=0).
// XCD map (R4/R6/R7-proven): xcd=blockIdx&7 owns mt in [xcd*32,+32).
// Epilogue additionally writes per-block column sums Pp[mt][n] (routing
// iter-1 partials, scale-free) -- shuffles + 1 KB LDS, NO atomics (R6's
// regression was the atomic/occupancy cost, not the fusion idea).
// ---------------------------------------------------------------------------
__global__ __launch_bounds__(256) void gemm_uhat(
    const float* __restrict__ A,             // [M_ROWS][D_IN] fp32
    const unsigned short* __restrict__ Bt,   // [N_COL][D_IN] bf16
    unsigned short* __restrict__ C,          // [M_ROWS][N_COL] bf16
    float* __restrict__ Pp) {                // [256][N_COL] fp32 col sums
  __shared__ __align__(16) float lAf[128 * 32];          // 16 KB
  __shared__ __align__(16) unsigned short lB[128 * 32];  // 8 KB
  __shared__ float cs2[2][128];

  const int t = threadIdx.x;
  const int wave = t >> 6, lane = t & 63;
  const int xcd = blockIdx.x & 7, local = blockIdx.x >> 3;
  const int mt = xcd * 32 + (local >> 3), nt = local & 7;
  const int m0 = mt * 128, n0 = nt * 128;
  const int wm = wave & 1, wn = wave >> 1;

  f32x4 acc[4][4] = {};

  // A staging: 16 segments of 8 rows (8 lanes/row, 16B=4 floats per lane);
  // fetch source chunk (lane&7)^(row&7) so LDS position p holds chunk p^(r&7).
  const int arow_in_seg = lane >> 3;
  const int achunk = lane & 7;
  // B staging: 8 segments of 16 rows (4 lanes/row, 16B=8 bf16 per lane).
  const int srow = lane >> 2;
  const int schunk = ((lane & 3) ^ ((srow >> 1) & 3)) * 8;

  for (int kt = 0; kt < D_IN / 32; ++kt) {
    const int k0 = kt * 32;
    __syncthreads();
    #pragma unroll
    for (int s0 = 0; s0 < 4; ++s0) {
      const int s = wave + s0 * 4;          // A segment 0..15
      const int arow = s * 8 + arow_in_seg;
      const int ac = (achunk ^ (arow & 7)) * 4;
      const float* ga = A + (size_t)(m0 + arow) * D_IN + k0 + ac;
      __builtin_amdgcn_global_load_lds(
          (const __attribute__((address_space(1))) void*)ga,
          (__attribute__((address_space(3))) void*)(lAf + s * 256), 16, 0, 0);
    }
    #pragma unroll
    for (int s0 = 0; s0 < 2; ++s0) {
      const int s = wave + s0 * 4;          // B segment 0..7
      const unsigned short* gb = Bt + (size_t)(n0 + s * 16 + srow) * D_IN + k0 + schunk;
      __builtin_amdgcn_global_load_lds(
          (const __attribute__((address_space(1))) void*)gb,
          (__attribute__((address_space(3))) void*)(lB + s * 512), 16, 0, 0);
    }
    __syncthreads();

    short8 af[4], bfr[4];
    const int rsel = lane & 15;
    const int q = lane >> 4;
    const int r7 = rsel & 7;
    #pragma unroll
    for (int tm = 0; tm < 4; tm++) {
      const int row = wm * 64 + tm * 16 + rsel;      // row&7 == r7
      const f32x4 x0 = *(const f32x4*)&lAf[row * 32 + ((2 * q) ^ r7) * 4];
      const f32x4 x1 = *(const f32x4*)&lAf[row * 32 + (((2 * q) | 1) ^ r7) * 4];
      uint4 pk;
      pk.x = pack_trunc(__float_as_uint(x0.x), __float_as_uint(x0.y));
      pk.y = pack_trunc(__float_as_uint(x0.z), __float_as_uint(x0.w));
      pk.z = pack_trunc(__float_as_uint(x1.x), __float_as_uint(x1.y));
      pk.w = pack_trunc(__float_as_uint(x1.z), __float_as_uint(x1.w));
      af[tm] = *(short8*)&pk;
    }
    const int koff = (q ^ ((rsel >> 1) & 3)) * 8;
    #pragma unroll
    for (int tn = 0; tn < 4; tn++)
      bfr[tn] = *(const short8*)&lB[(wn * 64 + tn * 16 + rsel) * 32 + koff];
    #pragma unroll
    for (int tm = 0; tm < 4; tm++)
      #pragma unroll
      for (int tn = 0; tn < 4; tn++)
        acc[tm][tn] = __builtin_amdgcn_mfma_f32_16x16x32_bf16(
            af[tm], bfr[tn], acc[tm][tn], 0, 0, 0);
  }

  // C/D layout col=lane&15, row=(lane>>4)*4+reg  [m89-verified]
  const int lrow = (lane >> 4) * 4, lcol = lane & 15;
  #pragma unroll
  for (int tm = 0; tm < 4; tm++)
    #pragma unroll
    for (int tn = 0; tn < 4; tn++)
      #pragma unroll
      for (int r = 0; r < 4; r++) {
        const int row = m0 + wm * 64 + tm * 16 + lrow + r;
        const int col = n0 + wn * 64 + tn * 16 + lcol;
        C[(size_t)row * N_COL + col] = f2bf_rne(acc[tm][tn][r]);
      }

  // Column sums over this block's 128 rows (routing iter-1 partials).
  // Within a wave: column col's 64-row sum lives across the 4 quads ->
  // xor-16/32 shuffles; then combine the wm pair through LDS (no atomics).
  #pragma unroll
  for (int tn = 0; tn < 4; tn++) {
    float p = 0.f;
    #pragma unroll
    for (int tm = 0; tm < 4; tm++)
      #pragma unroll
      for (int r = 0; r < 4; r++) p += acc[tm][tn][r];
    p += __shfl_xor(p, 16);
    p += __shfl_xor(p, 32);
    if (lane < 16) cs2[wm][wn * 64 + tn * 16 + lane] = p;
  }
  __syncthreads();
  if (t < 128)
    Pp[(size_t)mt * N_COL + n0 + t] = cs2[0][t] + cs2[1][t];
}

// ---------------------------------------------------------------------------
// Routing iteration: block=(b,jt4).  Phase A (redundant, cheap): sum nstrips
// 1024-float strips of Vin -> s, squash -> v.  Phase B: wave w handles
// jt=jt4*4+w (8 j's, fully unrolled so all 16 b128 loads issue up front);
// lane l holds uhat[b, i=l>>2, j, k=(l&3)*16..+16]; softmax over i via
// shuffles (no max-subtract, |b| bounded); 4-wave LDS reduce -> Pout.
// ---------------------------------------------------------------------------
__global__ __launch_bounds__(256) void route_mid(
    const unsigned short* __restrict__ uhat,
    const float* __restrict__ Vin,
    float* __restrict__ Pout,
    const int nstrips) {
  __shared__ float sq[16 * 68];
  __shared__ float red[4][1024];
  const int t = threadIdx.x;
  const int w = t >> 6, lane = t & 63;
  const int b = blockIdx.x >> 4, jt4 = blockIdx.x & 15;
  const int jt = jt4 * 4 + w;
  const int i_l = lane >> 2, c4 = lane & 3;

  float4 v4 = make_float4(0.f, 0.f, 0.f, 0.f);
  for (int s = 0; s < nstrips; ++s) {
    const float4 ps = *(const float4*)&Vin[((size_t)b * nstrips + s) * 1024 + t * 4];
    v4.x += ps.x; v4.y += ps.y; v4.z += ps.z; v4.w += ps.w;
  }
  float ss = v4.x * v4.x + v4.y * v4.y + v4.z * v4.z + v4.w * v4.w;
  #pragma unroll
  for (int d = 1; d < 16; d <<= 1) ss += __shfl_xor(ss, d);
  const float inv = 1.f / sqrtf(ss + 1e-7f);
  const int oi = t >> 4, ok = (t & 15) * 4;
  *(float4*)&sq[oi * 68 + ok] =
      make_float4(v4.x * inv, v4.y * inv, v4.z * inv, v4.w * inv);
  __syncthreads();

  float pv[16];
  #pragma unroll
  for (int q = 0; q < 4; q++)
    *(float4*)&pv[q * 4] = *(const float4*)&sq[i_l * 68 + c4 * 16 + q * 4];

  float acc[16];
  #pragma unroll
  for (int q = 0; q < 16; q++) acc[q] = 0.f;

  const unsigned short* ub =
      uhat + (size_t)(b * N_IN + jt * 8) * N_COL + lane * 16;

  #pragma unroll
  for (int jj = 0; jj < 8; ++jj, ub += N_COL) {
    const uint4 d0 = *(const uint4*)ub;
    const uint4 d1 = *(const uint4*)(ub + 8);
    float u[16];
    #define UNP(wd, o) { u[(o)] = bf2f((wd) & 0xffffu); u[(o)+1] = __uint_as_float((wd) & 0xffff0000u); }
    UNP(d0.x, 0) UNP(d0.y, 2) UNP(d0.z, 4) UNP(d0.w, 6)
    UNP(d1.x, 8) UNP(d1.y, 10) UNP(d1.z, 12) UNP(d1.w, 14)
    #undef UNP

    float dot = 0.f;
    #pragma unroll
    for (int q = 0; q < 16; q++) dot = fmaf(pv[q], u[q], dot);
    dot += __shfl_xor(dot, 1);
    dot += __shfl_xor(dot, 2);
    const float e = __expf(dot);
    float s = e;
    #pragma unroll
    for (int d = 4; d < 64; d <<= 1) s += __shfl_xor(s, d);
    const float c = e / s;
    #pragma unroll
    for (int q = 0; q < 16; q++) acc[q] = fmaf(c, u[q], acc[q]);
  }

  #pragma unroll
  for (int q = 0; q < 4; q++)
    *(float4*)&red[w][lane * 16 + q * 4] = make_float4(
        acc[q * 4 + 0], acc[q * 4 + 1], acc[q * 4 + 2], acc[q * 4 + 3]);
  __syncthreads();
  float4 s4 = make_float4(0.f, 0.f, 0.f, 0.f);
  #pragma unroll
  for (int ww = 0; ww < 4; ++ww) {
    const float4 r = *(const float4*)&red[ww][t * 4];
    s4.x += r.x; s4.y += r.y; s4.z += r.z; s4.w += r.w;
  }
  *(float4*)&Pout[(size_t)blockIdx.x * 1024 + t * 4] = s4;
}

// ---------------------------------------------------------------------------
__global__ __launch_bounds__(64) void route_last(
    const float* __restrict__ P, float* __restrict__ dst) {
  const int bi = blockIdx.x;
  const int k = threadIdx.x;
  const int b = bi >> 4, i = bi & 15;
  const float* p = P + (size_t)b * 16 * 1024 + i * 64 + k;
  float s = 0.f;
  #pragma unroll
  for (int tt = 0; tt < 16; ++tt) s += p[(size_t)tt * 1024];
  float ss = s * s;
  #pragma unroll
  for (int d = 1; d < 64; d <<= 1) ss += __shfl_xor(ss, d);
  dst[bi * 64 + k] = s / sqrtf(ss + 1e-7f);
}

// ---------------------------------------------------------------------------
extern "C" void kernel_launch(void* const* d_in, const int* in_sizes, int n_in,
                              void* d_out, int out_size, void* d_ws, size_t ws_size,
                              hipStream_t stream) {
  const float* x = (const float*)d_in[0];   // [64][512][1024] fp32
  const float* W = (const float*)d_in[1];   // [1][1024][1024] fp32
  float* out = (float*)d_out;               // [64][16][64] fp32

  char* ws = (char*)d_ws;
  unsigned short* Wt   = (unsigned short*)ws;                        // 0..2 MB
  unsigned short* uhat = (unsigned short*)(ws + (size_t)(2 << 20));  // 2..66 MB
  float* Pp = (float*)(ws + (size_t)66 * (1 << 20));                 // 66..67 MB
  float* P1 = (float*)(ws + (size_t)67 * (1 << 20));                 // 67..71 MB
  float* P2 = (float*)(ws + (size_t)71 * (1 << 20));                 // 71..75 MB

  prep_w<<<1024, 256, 0, stream>>>(W, Wt);
  gemm_uhat<<<2048, 256, 0, stream>>>(x, Wt, uhat, Pp);
  route_mid<<<1024, 256, 0, stream>>>(uhat, Pp, P1, 4);   // routing iter 2
  route_mid<<<1024, 256, 0, stream>>>(uhat, P1, P2, 16);  // routing iter 3
  route_last<<<1024, 64, 0, stream>>>(P2, out);
}